// Round 12
// baseline (298.528 us; speedup 1.0000x reference)
//
#include <hip/hip_runtime.h>
#include <hip/hip_bf16.h>

// ---------- bf16 helpers (raw ushort storage) ----------
__device__ __forceinline__ float b2f(unsigned short u) {
    union { float f; unsigned int i; } v; v.i = ((unsigned int)u) << 16; return v.f;
}
__device__ __forceinline__ unsigned short f2b(float f) {
    union { float f; unsigned int i; } v; v.f = f;
    unsigned int i = v.i;
    return (unsigned short)((i + 0x7FFFu + ((i >> 16) & 1u)) >> 16);   // RNE
}

typedef __bf16 bf16x8 __attribute__((ext_vector_type(8)));
typedef float  f32x4  __attribute__((ext_vector_type(4)));

// R21/R22: 64-row / 512-thread / 8-wave mega, acc[4][2]=32 VGPR.
// R23: flat xb [M][128], single-pass gather.
// R24/R25 FAILED: cross-block fences -> L2 flush storms.
// R26: gather index-prefetch ~neutral.
// R27 FAILED: forced min-waves -> spill. 16 waves/CU is mega's ceiling.
// R28: vectorized prep + reorder. 292us.
// R29: memsetAsync(count) + fused prep/pack/hist kernel. 290.9us.
// R30: gather 2-way edge-split per node (32 lanes/node, shfl_down combine):
//   halves per-node serial batch chain + imbalance quantum, 2x wave count.
//   Decisive test: latency-bound -> -15-20us; BW-bound -> neutral (closed).
#define MROWS 64

// 256-col LDS tile: row stride 256, XOR-16B swizzle
__device__ __forceinline__ int idx256(int r, int c) {
    return r * 256 + (((c >> 3) ^ (r & 31)) << 3) + (c & 7);
}
// 128-col LDS tile
__device__ __forceinline__ int idx128(int r, int c) {
    return r * 128 + ((((c >> 3) ^ r) & 15) << 3) + (c & 7);
}

// xb: flat [node][128] bf16 = bf16([x|t])
// hin: flat [node][128] bf16 = bf16(x_in + sum_agg)  (gather folds x_in)

// ---------- K1 (R29): fused pack + xb prep + out/state zero + hist -----------
// count is pre-zeroed by hipMemsetAsync (the ONLY cross-phase ordering need).
__global__ __launch_bounds__(256) void fused_prep_kernel(
    const float* __restrict__ x, const float* __restrict__ t,
    const int* __restrict__ ei,
    const float* __restrict__ W1, const float* __restrict__ W2,
    const float* __restrict__ P1, const float* __restrict__ P2,
    unsigned short* __restrict__ W1h, unsigned short* __restrict__ W1l,
    unsigned short* __restrict__ W2h, unsigned short* __restrict__ W2l,
    unsigned short* __restrict__ P1h, unsigned short* __restrict__ P2h,
    unsigned short* __restrict__ xb,
    int* __restrict__ count, float* __restrict__ out,
    unsigned* __restrict__ state, int E, int M, int nb)
{
    int idx = blockIdx.x * 256 + threadIdx.x;   // over max(M*16, E)
    // ---- xb: 8 features/thread, uint4 store ----
    if (idx < M * 16) {
        int i = idx >> 4, j16 = idx & 15;
        int f0 = j16 * 8;
        float v[8];
        if (f0 + 8 <= 127) {
            __builtin_memcpy(v, x + (size_t)i * 127 + f0, 32);
        } else {                                // f0==120: last is t
            __builtin_memcpy(v, x + (size_t)i * 127 + f0, 28);
            v[7] = t[i];
        }
        union { unsigned short u[8]; uint4 q; } ob;
        #pragma unroll
        for (int j = 0; j < 8; ++j) ob.u[j] = f2b(v[j]);
        *(uint4*)(xb + (size_t)i * 128 + f0) = ob.q;
    }
    // ---- t_pred zero + scan-state zero (consumed by later kernels only) ----
    if (idx < M) out[idx] = 0.0f;
    if (idx < nb) state[idx] = 0u;
    // ---- hist (count pre-zeroed by memsetAsync) ----
    if (idx < E) {
        int s = ei[idx];
        int d = ei[E + idx];
        if ((unsigned)s < (unsigned)M && (unsigned)d < (unsigned)M)
            atomicAdd(&count[d], 1);
    }
    // ---- weight pack (262144 threads) ----
    const float* B; unsigned short *Bh, *Bl; int loc;
    if (idx < 128 * 256)       { B = W1; Bh = W1h; Bl = W1l; loc = idx; }
    else if (idx < 384 * 256)  { B = W2; Bh = W2h; Bl = W2l; loc = idx - 128 * 256; }
    else if (idx < 768 * 256)  { B = P1; Bh = P1h; Bl = nullptr; loc = idx - 384 * 256; }
    else if (idx < 1024 * 256) { B = P2; Bh = P2h; Bl = nullptr; loc = idx - 768 * 256; }
    else return;
    int j    = loc & 7;
    int lane = (loc >> 3) & 63;
    int nt   = (loc >> 9) & 15;
    int kt   = loc >> 13;
    int k = kt * 32 + ((lane >> 4) * 8) + j;
    int n = nt * 16 + (lane & 15);
    float w = B[k * 256 + n];
    unsigned short hi = f2b(w);
    Bh[loc] = hi;
    if (Bl) Bl[loc] = f2b(w - b2f(hi));
}

// ---------- fallback K1: pack weights only ----------
__global__ __launch_bounds__(256) void pack_all_init_kernel(
    const float* __restrict__ W1, const float* __restrict__ W2,
    const float* __restrict__ P1, const float* __restrict__ P2,
    unsigned short* __restrict__ W1h, unsigned short* __restrict__ W1l,
    unsigned short* __restrict__ W2h, unsigned short* __restrict__ W2l,
    unsigned short* __restrict__ P1h, unsigned short* __restrict__ P2h,
    int M)
{
    int idx = blockIdx.x * 256 + threadIdx.x;
    const float* B; unsigned short *Bh, *Bl; int loc;
    if (idx < 128 * 256)       { B = W1; Bh = W1h; Bl = W1l; loc = idx; }
    else if (idx < 384 * 256)  { B = W2; Bh = W2h; Bl = W2l; loc = idx - 128 * 256; }
    else if (idx < 768 * 256)  { B = P1; Bh = P1h; Bl = nullptr; loc = idx - 384 * 256; }
    else if (idx < 1024 * 256) { B = P2; Bh = P2h; Bl = nullptr; loc = idx - 768 * 256; }
    else return;
    int j    = loc & 7;
    int lane = (loc >> 3) & 63;
    int nt   = (loc >> 9) & 15;
    int kt   = loc >> 13;
    int k = kt * 32 + ((lane >> 4) * 8) + j;
    int n = nt * 16 + (lane & 15);
    float w = B[k * 256 + n];
    unsigned short hi = f2b(w);
    Bh[loc] = hi;
    if (Bl) Bl[loc] = f2b(w - b2f(hi));
}

// ---------- fallback prep: agg = 0; out[t_pred] = 0 ----------
__global__ __launch_bounds__(256) void prep_kernel(unsigned short* __restrict__ agg,
                                                   float* __restrict__ out, int M)
{
    int idx = blockIdx.x * 256 + threadIdx.x;
    if (idx < M * 128) agg[idx] = 0;
    if (idx < M) out[idx] = 0.0f;
}

// ---------- fallback scatter: bf16 packed global atomics ----------
__global__ __launch_bounds__(256) void scatter_kernel(
    const int* __restrict__ ei, const float* __restrict__ x,
    const float* __restrict__ t, unsigned short* __restrict__ agg, int E, int M)
{
    int e = blockIdx.x * 8 + (threadIdx.x >> 5);
    if (e >= E) return;
    int lane = threadIdx.x & 31;
    int s = ei[e];
    int d = ei[E + e];
    if ((unsigned)s >= (unsigned)M || (unsigned)d >= (unsigned)M) return;
    int f0 = lane * 4;
    const float* xr = x + (size_t)s * 127;
    float v0 = xr[f0];
    float v1 = xr[f0 + 1];
    float v2 = xr[f0 + 2];
    float v3 = (f0 + 3 < 127) ? xr[f0 + 3] : t[s];
    __hip_bfloat162* dp = (__hip_bfloat162*)(agg + (size_t)d * 128 + f0);
    __hip_bfloat162 a; a.x = __float2bfloat16(v0); a.y = __float2bfloat16(v1);
    __hip_bfloat162 b; b.x = __float2bfloat16(v2); b.y = __float2bfloat16(v3);
    unsafeAtomicAdd(dp,     a);
    unsafeAtomicAdd(dp + 1, b);
}

// ---------- K2: single-pass scan, PARALLEL poll ----------
__global__ __launch_bounds__(256) void scan_fused_kernel(
    const int* __restrict__ count, int* __restrict__ start,
    int* __restrict__ cursor, unsigned* __restrict__ state, int M, int nb)
{
    __shared__ int sb[256];
    __shared__ int pre[256];
    int b = blockIdx.x, tid = threadIdx.x;
    int i = b * 256 + tid;
    int v = (i < M) ? count[i] : 0;
    sb[tid] = v;
    __syncthreads();
    for (int off = 1; off < 256; off <<= 1) {
        int a = (tid >= off) ? sb[tid - off] : 0;
        __syncthreads();
        sb[tid] += a;
        __syncthreads();
    }
    int incl  = sb[tid];
    int total = sb[255];
    if (tid == 0) atomicExch(&state[b], (1u << 30) | (unsigned)total);
    // parallel poll: thread tid owns slot tid (nb <= 256)
    int mine = 0;
    if (tid < nb && tid < b) {
        unsigned s;
        do { s = atomicAdd(&state[tid], 0u); } while ((s >> 30) == 0u);
        mine = (int)(s & 0x3FFFFFFFu);
    }
    pre[tid] = mine;
    __syncthreads();
    #pragma unroll
    for (int off = 128; off > 0; off >>= 1) {
        if (tid < off) pre[tid] += pre[tid + off];
        __syncthreads();
    }
    int excl = pre[0] + incl - v;
    if (i < M) { start[i] = excl; cursor[i] = excl; }
    if (i == M - 1) start[M] = excl + v;
}

// ---------- K3: reorder (R28: 4 edges/thread, int4 ei loads) ----------
__global__ __launch_bounds__(256) void reorder_csr_kernel(
    const int* __restrict__ ei, int* __restrict__ cursor,
    int* __restrict__ sorted, int E, int M)
{
    int q = blockIdx.x * 256 + threadIdx.x;
    int e0 = q * 4;
    if (e0 >= E) return;
    if (e0 + 4 <= E && (E & 3) == 0) {
        int4 sv = *(const int4*)(ei + e0);
        int4 dv = *(const int4*)(ei + E + e0);
        int ss[4] = {sv.x, sv.y, sv.z, sv.w};
        int dd[4] = {dv.x, dv.y, dv.z, dv.w};
        #pragma unroll
        for (int g = 0; g < 4; ++g) {
            if ((unsigned)ss[g] < (unsigned)M && (unsigned)dd[g] < (unsigned)M) {
                int slot = atomicAdd(&cursor[dd[g]], 1);
                sorted[slot] = ss[g];
            }
        }
    } else {
        int e1 = (e0 + 4 < E) ? e0 + 4 : E;
        for (int e = e0; e < e1; ++e) {
            int s = ei[e], d = ei[E + e];
            if ((unsigned)s < (unsigned)M && (unsigned)d < (unsigned)M) {
                int slot = atomicAdd(&cursor[d], 1);
                sorted[slot] = s;
            }
        }
    }
}

// ---------- K4: CSR gather -> h_in. R30: 2-way edge-split per node -----------
// 32 lanes/node (2 sub-groups x 16 lanes); subs process interleaved GU-batches;
// partials combined via __shfl_down(.,16); sub0 adds own row LAST and stores.
// Slot order within a node is already nondeterministic (cursor atomics), so
// the split-sum order change is within existing tolerance behavior.
#define GU 8
__global__ __launch_bounds__(256) void gather_csr_kernel(
    const unsigned short* __restrict__ xb, const int* __restrict__ sorted,
    const int* __restrict__ start, unsigned short* __restrict__ hin, int M)
{
    int node = blockIdx.x * 8 + (threadIdx.x >> 5);
    if (node >= M) return;
    int sub = (threadIdx.x >> 4) & 1;          // 2 edge sub-groups per node
    int l16 = threadIdx.x & 15;                // 16 lanes x uint4 = 256 B row
    const unsigned short* xp = xb + l16 * 8;
    int s0 = start[node], s1 = start[node + 1];
    uint4 own = *(const uint4*)(xp + (size_t)node * 128);   // issue early
    float a[8];
    #pragma unroll
    for (int j = 0; j < 8; ++j) a[j] = 0.f;
    int first = s0 + sub * GU;
    if (first < s1) {
        int last = s1 - 1;
        int idx[GU];
        #pragma unroll
        for (int g = 0; g < GU; ++g) {          // prologue: this sub's batch 0
            int i = first + g;
            idx[g] = sorted[(i < s1) ? i : last];
        }
        for (int base = first; base < s1; base += 2 * GU) {
            uint4 rv[GU];
            #pragma unroll
            for (int g = 0; g < GU; ++g)        // row loads for current batch
                rv[g] = *(const uint4*)(xp + (size_t)idx[g] * 128);
            int nb2 = base + 2 * GU;
            if (nb2 < s1) {
                #pragma unroll
                for (int g = 0; g < GU; ++g) {  // prefetch next batch indices
                    int i = nb2 + g;
                    idx[g] = sorted[(i < s1) ? i : last];
                }
            }
            #pragma unroll
            for (int g = 0; g < GU; ++g) {
                if (base + g < s1) {
                    a[0] += b2f((unsigned short)(rv[g].x & 0xffff));
                    a[1] += b2f((unsigned short)(rv[g].x >> 16));
                    a[2] += b2f((unsigned short)(rv[g].y & 0xffff));
                    a[3] += b2f((unsigned short)(rv[g].y >> 16));
                    a[4] += b2f((unsigned short)(rv[g].z & 0xffff));
                    a[5] += b2f((unsigned short)(rv[g].z >> 16));
                    a[6] += b2f((unsigned short)(rv[g].w & 0xffff));
                    a[7] += b2f((unsigned short)(rv[g].w >> 16));
                }
            }
        }
    }
    // combine sub partials within the wave (lanes L <- L+16)
    #pragma unroll
    for (int j = 0; j < 8; ++j) a[j] += __shfl_down(a[j], 16);
    if (sub == 0) {
        // own row added last (same position in sum as all prior versions)
        a[0] += b2f((unsigned short)(own.x & 0xffff));
        a[1] += b2f((unsigned short)(own.x >> 16));
        a[2] += b2f((unsigned short)(own.y & 0xffff));
        a[3] += b2f((unsigned short)(own.y >> 16));
        a[4] += b2f((unsigned short)(own.z & 0xffff));
        a[5] += b2f((unsigned short)(own.z >> 16));
        a[6] += b2f((unsigned short)(own.w & 0xffff));
        a[7] += b2f((unsigned short)(own.w >> 16));
        uint4 w;
        w.x = (unsigned)f2b(a[0]) | ((unsigned)f2b(a[1]) << 16);
        w.y = (unsigned)f2b(a[2]) | ((unsigned)f2b(a[3]) << 16);
        w.z = (unsigned)f2b(a[4]) | ((unsigned)f2b(a[5]) << 16);
        w.w = (unsigned)f2b(a[6]) | ((unsigned)f2b(a[7]) << 16);
        *(uint4*)(hin + (size_t)node * 128 + l16 * 8) = w;
    }
}

// ---------- K5: mega — 4 GEMMs + final dot, 64-row / 512-thread blocks -------
// W1/W2: split hi+lo (2 MFMAs); P1/P2: hi only (1 MFMA).
// 8 waves; wave w computes ALL 64 rows (rt=4) x cols [w*32, w*32+32) (nt=2).
// acc[4][2] = 32 VGPR/wave. Block reads full weight set exactly once.
// NO __launch_bounds__ min-waves (R9/R11/R27: forced caps -> spill).
template<bool HIN>
__global__ __launch_bounds__(512) void mega_kernel(
    const float* __restrict__ x, const float* __restrict__ t,
    const unsigned short* __restrict__ xb,   // flat [M][128]
    const unsigned short* __restrict__ hin,  // HIN: [M][128] bf16; else bf16 agg
    const unsigned short* __restrict__ W1h, const unsigned short* __restrict__ W1l,
    const float* __restrict__ b1,
    const unsigned short* __restrict__ W2h, const unsigned short* __restrict__ W2l,
    const float* __restrict__ b2,
    const unsigned short* __restrict__ P1h, const float* __restrict__ pb1,
    const unsigned short* __restrict__ P2h, const float* __restrict__ pb2,
    const float* __restrict__ P3, const float* __restrict__ pb3,
    float* __restrict__ out, int M)
{
    __shared__ unsigned short U[MROWS * 256];   // 32 KB: h_in -> h1 -> h -> p1
    __shared__ float red[8 * MROWS];            // 2 KB

    const int wave = threadIdx.x >> 6;          // 0..7
    const int lane = threadIdx.x & 63;
    const int lr   = lane & 15;
    const int quad = lane >> 4;
    const int lk   = quad * 8;
    const int rbase = quad * 4;
    const int row0 = blockIdx.x * MROWS;
    const int ntg0 = wave * 2;                  // 2 col-tiles (32 cols) per wave

    // ---- U[idx128] = h_in: 64 rows x 128 cols ----
    {
        int r = threadIdx.x >> 3;            // 0..63
        int q = threadIdx.x & 7;             // 0..7, 16 cols each
        int gr = row0 + r; if (gr >= M) gr = M - 1;
        #pragma unroll
        for (int c8 = 0; c8 < 2; ++c8) {
            int c0 = q * 16 + c8 * 8;
            if (HIN) {
                uint4 v = *(const uint4*)(hin + (size_t)gr * 128 + c0);
                *(uint4*)&U[idx128(r, c0)] = v;
            } else {
                const unsigned short* ar = hin + (size_t)gr * 128 + c0;
                uint4 u = *(const uint4*)ar;
                float av[8];
                av[0]=b2f((unsigned short)(u.x&0xffff)); av[1]=b2f((unsigned short)(u.x>>16));
                av[2]=b2f((unsigned short)(u.y&0xffff)); av[3]=b2f((unsigned short)(u.y>>16));
                av[4]=b2f((unsigned short)(u.z&0xffff)); av[5]=b2f((unsigned short)(u.z>>16));
                av[6]=b2f((unsigned short)(u.w&0xffff)); av[7]=b2f((unsigned short)(u.w>>16));
                const float* xr = x + (size_t)gr * 127;
                union { unsigned short u[8]; uint4 v; } ob;
                #pragma unroll
                for (int j = 0; j < 8; ++j) {
                    int f = c0 + j;
                    float xval = (f < 127) ? xr[f] : t[gr];
                    ob.u[j] = f2b(xval + av[j]);
                }
                *(uint4*)&U[idx128(r, c0)] = ob.v;
            }
        }
    }
    __syncthreads();

    f32x4 acc[4][2];
    const f32x4 zero = {0.f, 0.f, 0.f, 0.f};

    // ======== stage 1: h1 = relu(h_in @ W1 + b1); U := h1 ========
    #pragma unroll
    for (int nt = 0; nt < 2; ++nt)
        #pragma unroll
        for (int rt = 0; rt < 4; ++rt) acc[rt][nt] = zero;

    for (int kt = 0; kt < 4; ++kt) {
        bf16x8 a[4];
        #pragma unroll
        for (int rt = 0; rt < 4; ++rt)
            a[rt] = *(const bf16x8*)&U[idx128(rt * 16 + lr, kt * 32 + lk)];
        #pragma unroll
        for (int nt = 0; nt < 2; ++nt) {
            size_t bofs = (size_t)((kt * 16 + ntg0 + nt) * 64 + lane) * 8;
            bf16x8 bh = *(const bf16x8*)(W1h + bofs);
            bf16x8 bl = *(const bf16x8*)(W1l + bofs);
            #pragma unroll
            for (int rt = 0; rt < 4; ++rt) {
                acc[rt][nt] = __builtin_amdgcn_mfma_f32_16x16x32_bf16(a[rt], bl, acc[rt][nt], 0, 0, 0);
                acc[rt][nt] = __builtin_amdgcn_mfma_f32_16x16x32_bf16(a[rt], bh, acc[rt][nt], 0, 0, 0);
            }
        }
    }
    __syncthreads();
    #pragma unroll
    for (int nt = 0; nt < 2; ++nt) {
        int col = (ntg0 + nt) * 16 + lr;
        float bv = b1[col];
        #pragma unroll
        for (int rt = 0; rt < 4; ++rt)
            #pragma unroll
            for (int r4 = 0; r4 < 4; ++r4)
                U[idx256(rt * 16 + rbase + r4, col)] = f2b(fmaxf(acc[rt][nt][r4] + bv, 0.f));
    }
    __syncthreads();

    // ======== stage 2: h = tanh(relu(h1 @ W2 + b2)); U := h ========
    #pragma unroll
    for (int nt = 0; nt < 2; ++nt)
        #pragma unroll
        for (int rt = 0; rt < 4; ++rt) acc[rt][nt] = zero;

    for (int kt = 0; kt < 8; ++kt) {
        bf16x8 a[4];
        #pragma unroll
        for (int rt = 0; rt < 4; ++rt)
            a[rt] = *(const bf16x8*)&U[idx256(rt * 16 + lr, kt * 32 + lk)];
        #pragma unroll
        for (int nt = 0; nt < 2; ++nt) {
            size_t bofs = (size_t)((kt * 16 + ntg0 + nt) * 64 + lane) * 8;
            bf16x8 bh = *(const bf16x8*)(W2h + bofs);
            bf16x8 bl = *(const bf16x8*)(W2l + bofs);
            #pragma unroll
            for (int rt = 0; rt < 4; ++rt) {
                acc[rt][nt] = __builtin_amdgcn_mfma_f32_16x16x32_bf16(a[rt], bl, acc[rt][nt], 0, 0, 0);
                acc[rt][nt] = __builtin_amdgcn_mfma_f32_16x16x32_bf16(a[rt], bh, acc[rt][nt], 0, 0, 0);
            }
        }
    }
    __syncthreads();
    #pragma unroll
    for (int nt = 0; nt < 2; ++nt) {
        int col = (ntg0 + nt) * 16 + lr;
        float bv = b2[col];
        #pragma unroll
        for (int rt = 0; rt < 4; ++rt)
            #pragma unroll
            for (int r4 = 0; r4 < 4; ++r4) {
                float v = fmaxf(acc[rt][nt][r4] + bv, 0.f);   // relu∘tanh == tanh∘relu
                float e = __expf(-2.f * v);
                U[idx256(rt * 16 + rbase + r4, col)] = f2b((1.f - e) / (1.f + e));
            }
    }
    __syncthreads();

    // ======== stage 3: p1 = lrelu([h | x_in] @ P1 + pb1); U := p1 ========
    #pragma unroll
    for (int nt = 0; nt < 2; ++nt)
        #pragma unroll
        for (int rt = 0; rt < 4; ++rt) acc[rt][nt] = zero;

    for (int kt = 0; kt < 12; ++kt) {
        bf16x8 a[4];
        if (kt < 8) {
            #pragma unroll
            for (int rt = 0; rt < 4; ++rt)
                a[rt] = *(const bf16x8*)&U[idx256(rt * 16 + lr, kt * 32 + lk)];
        } else if (HIN) {
            #pragma unroll
            for (int rt = 0; rt < 4; ++rt) {
                int r = row0 + rt * 16 + lr; if (r >= M) r = M - 1;
                int c0 = (kt - 8) * 32 + lk;
                a[rt] = *(const bf16x8*)(xb + (size_t)r * 128 + c0);
            }
        } else {
            #pragma unroll
            for (int rt = 0; rt < 4; ++rt) {
                int r = row0 + rt * 16 + lr; if (r >= M) r = M - 1;
                int c0 = (kt - 8) * 32 + lk;
                const float* xr = x + (size_t)r * 127;
                union { unsigned short u[8]; bf16x8 v; } au;
                #pragma unroll
                for (int j = 0; j < 8; ++j) {
                    int f = c0 + j;
                    au.u[j] = f2b((f < 127) ? xr[f] : t[r]);
                }
                a[rt] = au.v;
            }
        }
        #pragma unroll
        for (int nt = 0; nt < 2; ++nt) {
            size_t bofs = (size_t)((kt * 16 + ntg0 + nt) * 64 + lane) * 8;
            bf16x8 bh = *(const bf16x8*)(P1h + bofs);
            #pragma unroll
            for (int rt = 0; rt < 4; ++rt)
                acc[rt][nt] = __builtin_amdgcn_mfma_f32_16x16x32_bf16(a[rt], bh, acc[rt][nt], 0, 0, 0);
        }
    }
    __syncthreads();
    #pragma unroll
    for (int nt = 0; nt < 2; ++nt) {
        int col = (ntg0 + nt) * 16 + lr;
        float bv = pb1[col];
        #pragma unroll
        for (int rt = 0; rt < 4; ++rt)
            #pragma unroll
            for (int r4 = 0; r4 < 4; ++r4) {
                float v = acc[rt][nt][r4] + bv;
                U[idx256(rt * 16 + rbase + r4, col)] = f2b((v > 0.f) ? v : 0.2f * v);
            }
    }
    __syncthreads();

    // ======== stage 4: p2 = lrelu(p1 @ P2 + pb2); pred = p2 . P3 + pb3 ========
    #pragma unroll
    for (int nt = 0; nt < 2; ++nt)
        #pragma unroll
        for (int rt = 0; rt < 4; ++rt) acc[rt][nt] = zero;

    for (int kt = 0; kt < 8; ++kt) {
        bf16x8 a[4];
        #pragma unroll
        for (int rt = 0; rt < 4; ++rt)
            a[rt] = *(const bf16x8*)&U[idx256(rt * 16 + lr, kt * 32 + lk)];
        #pragma unroll
        for (int nt = 0; nt < 2; ++nt) {
            size_t bofs = (size_t)((kt * 16 + ntg0 + nt) * 64 + lane) * 8;
            bf16x8 bh = *(const bf16x8*)(P2h + bofs);
            #pragma unroll
            for (int rt = 0; rt < 4; ++rt)
                acc[rt][nt] = __builtin_amdgcn_mfma_f32_16x16x32_bf16(a[rt], bh, acc[rt][nt], 0, 0, 0);
        }
    }
    float part[4][4];
    #pragma unroll
    for (int rt = 0; rt < 4; ++rt)
        #pragma unroll
        for (int r4 = 0; r4 < 4; ++r4) part[rt][r4] = 0.f;
    #pragma unroll
    for (int nt = 0; nt < 2; ++nt) {
        int col = (ntg0 + nt) * 16 + lr;
        float bv = pb2[col];
        float p3 = P3[col];
        #pragma unroll
        for (int rt = 0; rt < 4; ++rt)
            #pragma unroll
            for (int r4 = 0; r4 < 4; ++r4) {
                float v = acc[rt][nt][r4] + bv;
                v = (v > 0.f) ? v : 0.2f * v;
                part[rt][r4] += v * p3;
            }
    }
    #pragma unroll
    for (int rt = 0; rt < 4; ++rt)
        #pragma unroll
        for (int r4 = 0; r4 < 4; ++r4) {
            float s = part[rt][r4];
            s += __shfl_xor(s, 1);
            s += __shfl_xor(s, 2);
            s += __shfl_xor(s, 4);
            s += __shfl_xor(s, 8);
            if (lr == 0) red[wave * MROWS + rt * 16 + rbase + r4] = s;
        }
    __syncthreads();
    if ((int)threadIdx.x < MROWS) {
        int row = row0 + threadIdx.x;
        if (row < M) {
            float s = pb3[0];
            #pragma unroll
            for (int w = 0; w < 8; ++w) s += red[w * MROWS + threadIdx.x];
            out[M + row] = s;
        }
    }
}

extern "C" void kernel_launch(void* const* d_in, const int* in_sizes, int n_in,
                              void* d_out, int out_size, void* d_ws, size_t ws_size,
                              hipStream_t stream)
{
    const int M = in_sizes[1];                 // 50000
    const int E = in_sizes[3] / 2;             // 800000
    const float* x   = (const float*)d_in[0];
    const float* t   = (const float*)d_in[1];
    const int*   ei  = (const int*)d_in[3];
    const float* W1  = (const float*)d_in[4];
    const float* b1  = (const float*)d_in[5];
    const float* W2  = (const float*)d_in[6];
    const float* b2  = (const float*)d_in[7];
    const float* P1  = (const float*)d_in[8];
    const float* pb1 = (const float*)d_in[9];
    const float* P2  = (const float*)d_in[10];
    const float* pb2 = (const float*)d_in[11];
    const float* P3  = (const float*)d_in[12];
    const float* pb3 = (const float*)d_in[13];
    float* out = (float*)d_out;

    const size_t hinB  = (size_t)M * 128 * 2;   // bf16 h_in (or bf16 agg in fallback)
    const size_t xbB   = (size_t)M * 128 * 2;
    const size_t wB    = (size_t)(128 * 2 + 256 * 2 + 384 + 256) * 256 * 2;  // 720 KB
    const size_t sortB = (size_t)E * 4;
    const int    nb    = (M + 255) / 256;       // 196 scan blocks (<= 256 for co-residency)
    const size_t csrB  = (size_t)(3 * M + 2 + nb) * 4;
    char* ws = (char*)d_ws;
    auto al = [](size_t v) { return (v + 255) & ~(size_t)255; };

    bool tier = (ws_size >= al(hinB) + al(xbB) + al(wB) + al(sortB) + al(csrB) + 4096) && nb <= 256;

    unsigned short* hin = (unsigned short*)ws;
    unsigned short* xb  = (unsigned short*)(ws + al(hinB));
    unsigned short* W1h = (unsigned short*)((char*)xb + al(xbB));
    unsigned short* W1l = W1h + 128 * 256;
    unsigned short* W2h = W1l + 128 * 256;
    unsigned short* W2l = W2h + 256 * 256;
    unsigned short* P1h = W2l + 256 * 256;
    unsigned short* P2h = P1h + 384 * 256;
    int* sorted = (int*)(P2h + 256 * 256);
    int* count  = sorted + E;
    int* start  = count + M;        // M+1 entries
    int* cursor = start + M + 1;
    unsigned* state = (unsigned*)(cursor + M);

    const int NM = (M + MROWS - 1) / MROWS;
    int prepN = (M * 16 > E) ? M * 16 : E;
    int prepB = (prepN + 255) / 256;
    int reoB  = ((E + 3) / 4 + 255) / 256;

    if (tier) {
        hipMemsetAsync(count, 0, (size_t)M * 4, stream);   // only cross-phase order need
        fused_prep_kernel<<<prepB, 256, 0, stream>>>(
            x, t, ei, W1, W2, P1, P2, W1h, W1l, W2h, W2l, P1h, P2h,
            xb, count, out, state, E, M, nb);
        scan_fused_kernel<<<nb, 256, 0, stream>>>(count, start, cursor, state, M, nb);
        reorder_csr_kernel<<<reoB, 256, 0, stream>>>(ei, cursor, sorted, E, M);
        gather_csr_kernel<<<(M + 7) / 8, 256, 0, stream>>>(xb, sorted, start, hin, M);
        mega_kernel<true><<<NM, 512, 0, stream>>>(
            x, t, xb, hin, W1h, W1l, b1, W2h, W2l, b2,
            P1h, pb1, P2h, pb2, P3, pb3, out, M);
    } else {
        pack_all_init_kernel<<<1024, 256, 0, stream>>>(
            W1, W2, P1, P2, W1h, W1l, W2h, W2l, P1h, P2h, M);
        int pxb = (M * 128 + 255) / 256;
        prep_kernel<<<pxb, 256, 0, stream>>>(hin, out, M);
        scatter_kernel<<<(E + 7) / 8, 256, 0, stream>>>(ei, x, t, hin, E, M);
        mega_kernel<false><<<NM, 512, 0, stream>>>(
            x, t, nullptr, hin, W1h, W1l, b1, W2h, W2l, b2,
            P1h, pb1, P2h, pb2, P3, pb3, out, M);
    }
}

// Round 14
// 289.479 us; speedup vs baseline: 1.0313x; 1.0313x over previous
//
#include <hip/hip_runtime.h>
#include <hip/hip_bf16.h>

// ---------- bf16 helpers (raw ushort storage) ----------
__device__ __forceinline__ float b2f(unsigned short u) {
    union { float f; unsigned int i; } v; v.i = ((unsigned int)u) << 16; return v.f;
}
__device__ __forceinline__ unsigned short f2b(float f) {
    union { float f; unsigned int i; } v; v.f = f;
    unsigned int i = v.i;
    return (unsigned short)((i + 0x7FFFu + ((i >> 16) & 1u)) >> 16);   // RNE
}

typedef __bf16 bf16x8 __attribute__((ext_vector_type(8)));
typedef float  f32x4  __attribute__((ext_vector_type(4)));

// Session ledger:
// R21/R22: 64-row / 512-thread / 8-wave mega, acc[4][2]=32 VGPR. mega 87-94us.
// R23: flat xb [M][128], single-pass gather.
// R24/R25 FAILED: cross-block fences -> L2 flush storms on non-coherent
//   per-XCD L2. Launch boundary is the cheapest global barrier.
// R26: gather index-prefetch ~neutral.
// R27 FAILED: forced min-waves -> 32 VGPR -> spill. 16 waves/CU is mega's
//   ceiling (3rd failure: R9/R11/R27 — knob retired).
// R28: vectorized prep (8 feats/thread) + reorder (4 edges/thread). 292us.
// R29: memsetAsync(count) + fused prep/pack/hist kernel. 290.9us (BEST).
// R30 FAILED: gather 2-way edge-split regressed (298.5us) -> gather is
//   random-read-BW-bound; parallelism adds only overhead. Gather CLOSED.
// R31/R32: exact revert to R29 (best verified build). R31 bench was an
//   infra failure (container failed twice) — identical resubmit.
#define MROWS 64

// 256-col LDS tile: row stride 256, XOR-16B swizzle
__device__ __forceinline__ int idx256(int r, int c) {
    return r * 256 + (((c >> 3) ^ (r & 31)) << 3) + (c & 7);
}
// 128-col LDS tile
__device__ __forceinline__ int idx128(int r, int c) {
    return r * 128 + ((((c >> 3) ^ r) & 15) << 3) + (c & 7);
}

// xb: flat [node][128] bf16 = bf16([x|t])
// hin: flat [node][128] bf16 = bf16(x_in + sum_agg)  (gather folds x_in)

// ---------- K1 (R29): fused pack + xb prep + out/state zero + hist -----------
// count is pre-zeroed by hipMemsetAsync (the ONLY cross-phase ordering need).
__global__ __launch_bounds__(256) void fused_prep_kernel(
    const float* __restrict__ x, const float* __restrict__ t,
    const int* __restrict__ ei,
    const float* __restrict__ W1, const float* __restrict__ W2,
    const float* __restrict__ P1, const float* __restrict__ P2,
    unsigned short* __restrict__ W1h, unsigned short* __restrict__ W1l,
    unsigned short* __restrict__ W2h, unsigned short* __restrict__ W2l,
    unsigned short* __restrict__ P1h, unsigned short* __restrict__ P2h,
    unsigned short* __restrict__ xb,
    int* __restrict__ count, float* __restrict__ out,
    unsigned* __restrict__ state, int E, int M, int nb)
{
    int idx = blockIdx.x * 256 + threadIdx.x;   // over max(M*16, E)
    // ---- xb: 8 features/thread, uint4 store ----
    if (idx < M * 16) {
        int i = idx >> 4, j16 = idx & 15;
        int f0 = j16 * 8;
        float v[8];
        if (f0 + 8 <= 127) {
            __builtin_memcpy(v, x + (size_t)i * 127 + f0, 32);
        } else {                                // f0==120: last is t
            __builtin_memcpy(v, x + (size_t)i * 127 + f0, 28);
            v[7] = t[i];
        }
        union { unsigned short u[8]; uint4 q; } ob;
        #pragma unroll
        for (int j = 0; j < 8; ++j) ob.u[j] = f2b(v[j]);
        *(uint4*)(xb + (size_t)i * 128 + f0) = ob.q;
    }
    // ---- t_pred zero + scan-state zero (consumed by later kernels only) ----
    if (idx < M) out[idx] = 0.0f;
    if (idx < nb) state[idx] = 0u;
    // ---- hist (count pre-zeroed by memsetAsync) ----
    if (idx < E) {
        int s = ei[idx];
        int d = ei[E + idx];
        if ((unsigned)s < (unsigned)M && (unsigned)d < (unsigned)M)
            atomicAdd(&count[d], 1);
    }
    // ---- weight pack (262144 threads) ----
    const float* B; unsigned short *Bh, *Bl; int loc;
    if (idx < 128 * 256)       { B = W1; Bh = W1h; Bl = W1l; loc = idx; }
    else if (idx < 384 * 256)  { B = W2; Bh = W2h; Bl = W2l; loc = idx - 128 * 256; }
    else if (idx < 768 * 256)  { B = P1; Bh = P1h; Bl = nullptr; loc = idx - 384 * 256; }
    else if (idx < 1024 * 256) { B = P2; Bh = P2h; Bl = nullptr; loc = idx - 768 * 256; }
    else return;
    int j    = loc & 7;
    int lane = (loc >> 3) & 63;
    int nt   = (loc >> 9) & 15;
    int kt   = loc >> 13;
    int k = kt * 32 + ((lane >> 4) * 8) + j;
    int n = nt * 16 + (lane & 15);
    float w = B[k * 256 + n];
    unsigned short hi = f2b(w);
    Bh[loc] = hi;
    if (Bl) Bl[loc] = f2b(w - b2f(hi));
}

// ---------- fallback K1: pack weights only ----------
__global__ __launch_bounds__(256) void pack_all_init_kernel(
    const float* __restrict__ W1, const float* __restrict__ W2,
    const float* __restrict__ P1, const float* __restrict__ P2,
    unsigned short* __restrict__ W1h, unsigned short* __restrict__ W1l,
    unsigned short* __restrict__ W2h, unsigned short* __restrict__ W2l,
    unsigned short* __restrict__ P1h, unsigned short* __restrict__ P2h,
    int M)
{
    int idx = blockIdx.x * 256 + threadIdx.x;
    const float* B; unsigned short *Bh, *Bl; int loc;
    if (idx < 128 * 256)       { B = W1; Bh = W1h; Bl = W1l; loc = idx; }
    else if (idx < 384 * 256)  { B = W2; Bh = W2h; Bl = W2l; loc = idx - 128 * 256; }
    else if (idx < 768 * 256)  { B = P1; Bh = P1h; Bl = nullptr; loc = idx - 384 * 256; }
    else if (idx < 1024 * 256) { B = P2; Bh = P2h; Bl = nullptr; loc = idx - 768 * 256; }
    else return;
    int j    = loc & 7;
    int lane = (loc >> 3) & 63;
    int nt   = (loc >> 9) & 15;
    int kt   = loc >> 13;
    int k = kt * 32 + ((lane >> 4) * 8) + j;
    int n = nt * 16 + (lane & 15);
    float w = B[k * 256 + n];
    unsigned short hi = f2b(w);
    Bh[loc] = hi;
    if (Bl) Bl[loc] = f2b(w - b2f(hi));
}

// ---------- fallback prep: agg = 0; out[t_pred] = 0 ----------
__global__ __launch_bounds__(256) void prep_kernel(unsigned short* __restrict__ agg,
                                                   float* __restrict__ out, int M)
{
    int idx = blockIdx.x * 256 + threadIdx.x;
    if (idx < M * 128) agg[idx] = 0;
    if (idx < M) out[idx] = 0.0f;
}

// ---------- fallback scatter: bf16 packed global atomics ----------
__global__ __launch_bounds__(256) void scatter_kernel(
    const int* __restrict__ ei, const float* __restrict__ x,
    const float* __restrict__ t, unsigned short* __restrict__ agg, int E, int M)
{
    int e = blockIdx.x * 8 + (threadIdx.x >> 5);
    if (e >= E) return;
    int lane = threadIdx.x & 31;
    int s = ei[e];
    int d = ei[E + e];
    if ((unsigned)s >= (unsigned)M || (unsigned)d >= (unsigned)M) return;
    int f0 = lane * 4;
    const float* xr = x + (size_t)s * 127;
    float v0 = xr[f0];
    float v1 = xr[f0 + 1];
    float v2 = xr[f0 + 2];
    float v3 = (f0 + 3 < 127) ? xr[f0 + 3] : t[s];
    __hip_bfloat162* dp = (__hip_bfloat162*)(agg + (size_t)d * 128 + f0);
    __hip_bfloat162 a; a.x = __float2bfloat16(v0); a.y = __float2bfloat16(v1);
    __hip_bfloat162 b; b.x = __float2bfloat16(v2); b.y = __float2bfloat16(v3);
    unsafeAtomicAdd(dp,     a);
    unsafeAtomicAdd(dp + 1, b);
}

// ---------- K2: single-pass scan, PARALLEL poll ----------
__global__ __launch_bounds__(256) void scan_fused_kernel(
    const int* __restrict__ count, int* __restrict__ start,
    int* __restrict__ cursor, unsigned* __restrict__ state, int M, int nb)
{
    __shared__ int sb[256];
    __shared__ int pre[256];
    int b = blockIdx.x, tid = threadIdx.x;
    int i = b * 256 + tid;
    int v = (i < M) ? count[i] : 0;
    sb[tid] = v;
    __syncthreads();
    for (int off = 1; off < 256; off <<= 1) {
        int a = (tid >= off) ? sb[tid - off] : 0;
        __syncthreads();
        sb[tid] += a;
        __syncthreads();
    }
    int incl  = sb[tid];
    int total = sb[255];
    if (tid == 0) atomicExch(&state[b], (1u << 30) | (unsigned)total);
    // parallel poll: thread tid owns slot tid (nb <= 256)
    int mine = 0;
    if (tid < nb && tid < b) {
        unsigned s;
        do { s = atomicAdd(&state[tid], 0u); } while ((s >> 30) == 0u);
        mine = (int)(s & 0x3FFFFFFFu);
    }
    pre[tid] = mine;
    __syncthreads();
    #pragma unroll
    for (int off = 128; off > 0; off >>= 1) {
        if (tid < off) pre[tid] += pre[tid + off];
        __syncthreads();
    }
    int excl = pre[0] + incl - v;
    if (i < M) { start[i] = excl; cursor[i] = excl; }
    if (i == M - 1) start[M] = excl + v;
}

// ---------- K3: reorder (R28: 4 edges/thread, int4 ei loads) ----------
__global__ __launch_bounds__(256) void reorder_csr_kernel(
    const int* __restrict__ ei, int* __restrict__ cursor,
    int* __restrict__ sorted, int E, int M)
{
    int q = blockIdx.x * 256 + threadIdx.x;
    int e0 = q * 4;
    if (e0 >= E) return;
    if (e0 + 4 <= E && (E & 3) == 0) {
        int4 sv = *(const int4*)(ei + e0);
        int4 dv = *(const int4*)(ei + E + e0);
        int ss[4] = {sv.x, sv.y, sv.z, sv.w};
        int dd[4] = {dv.x, dv.y, dv.z, dv.w};
        #pragma unroll
        for (int g = 0; g < 4; ++g) {
            if ((unsigned)ss[g] < (unsigned)M && (unsigned)dd[g] < (unsigned)M) {
                int slot = atomicAdd(&cursor[dd[g]], 1);
                sorted[slot] = ss[g];
            }
        }
    } else {
        int e1 = (e0 + 4 < E) ? e0 + 4 : E;
        for (int e = e0; e < e1; ++e) {
            int s = ei[e], d = ei[E + e];
            if ((unsigned)s < (unsigned)M && (unsigned)d < (unsigned)M) {
                int slot = atomicAdd(&cursor[d], 1);
                sorted[slot] = s;
            }
        }
    }
}

// ---------- K4: CSR gather -> h_in. R26 form (R30 split reverted) ------------
#define GU 8
__global__ __launch_bounds__(256) void gather_csr_kernel(
    const unsigned short* __restrict__ xb, const int* __restrict__ sorted,
    const int* __restrict__ start, unsigned short* __restrict__ hin, int M)
{
    int node = blockIdx.x * 16 + (threadIdx.x >> 4);
    if (node >= M) return;
    int l16 = threadIdx.x & 15;                // 16 lanes x uint4 = 256 B row
    const unsigned short* xp = xb + l16 * 8;
    int s0 = start[node], s1 = start[node + 1];
    uint4 own = *(const uint4*)(xp + (size_t)node * 128);   // issue early
    float a[8];
    #pragma unroll
    for (int j = 0; j < 8; ++j) a[j] = 0.f;
    if (s0 < s1) {
        int last = s1 - 1;
        int idx[GU];
        #pragma unroll
        for (int g = 0; g < GU; ++g) {          // prologue: batch-0 indices
            int i = s0 + g;
            idx[g] = sorted[(i < s1) ? i : last];
        }
        for (int base = s0; base < s1; base += GU) {
            uint4 rv[GU];
            #pragma unroll
            for (int g = 0; g < GU; ++g)        // row loads for current batch
                rv[g] = *(const uint4*)(xp + (size_t)idx[g] * 128);
            int nb = base + GU;
            if (nb < s1) {
                #pragma unroll
                for (int g = 0; g < GU; ++g) {  // prefetch next batch indices
                    int i = nb + g;             // (in flight during row waits)
                    idx[g] = sorted[(i < s1) ? i : last];
                }
            }
            #pragma unroll
            for (int g = 0; g < GU; ++g) {
                if (base + g < s1) {
                    a[0] += b2f((unsigned short)(rv[g].x & 0xffff));
                    a[1] += b2f((unsigned short)(rv[g].x >> 16));
                    a[2] += b2f((unsigned short)(rv[g].y & 0xffff));
                    a[3] += b2f((unsigned short)(rv[g].y >> 16));
                    a[4] += b2f((unsigned short)(rv[g].z & 0xffff));
                    a[5] += b2f((unsigned short)(rv[g].z >> 16));
                    a[6] += b2f((unsigned short)(rv[g].w & 0xffff));
                    a[7] += b2f((unsigned short)(rv[g].w >> 16));
                }
            }
        }
    }
    // own row added last: identical rounding to previous versions
    a[0] += b2f((unsigned short)(own.x & 0xffff));
    a[1] += b2f((unsigned short)(own.x >> 16));
    a[2] += b2f((unsigned short)(own.y & 0xffff));
    a[3] += b2f((unsigned short)(own.y >> 16));
    a[4] += b2f((unsigned short)(own.z & 0xffff));
    a[5] += b2f((unsigned short)(own.z >> 16));
    a[6] += b2f((unsigned short)(own.w & 0xffff));
    a[7] += b2f((unsigned short)(own.w >> 16));
    uint4 w;
    w.x = (unsigned)f2b(a[0]) | ((unsigned)f2b(a[1]) << 16);
    w.y = (unsigned)f2b(a[2]) | ((unsigned)f2b(a[3]) << 16);
    w.z = (unsigned)f2b(a[4]) | ((unsigned)f2b(a[5]) << 16);
    w.w = (unsigned)f2b(a[6]) | ((unsigned)f2b(a[7]) << 16);
    *(uint4*)(hin + (size_t)node * 128 + l16 * 8) = w;
}

// ---------- K5: mega — 4 GEMMs + final dot, 64-row / 512-thread blocks -------
// W1/W2: split hi+lo (2 MFMAs); P1/P2: hi only (1 MFMA).
// 8 waves; wave w computes ALL 64 rows (rt=4) x cols [w*32, w*32+32) (nt=2).
// acc[4][2] = 32 VGPR/wave. Block reads full weight set exactly once.
// NO __launch_bounds__ min-waves (R9/R11/R27: forced caps -> spill).
template<bool HIN>
__global__ __launch_bounds__(512) void mega_kernel(
    const float* __restrict__ x, const float* __restrict__ t,
    const unsigned short* __restrict__ xb,   // flat [M][128]
    const unsigned short* __restrict__ hin,  // HIN: [M][128] bf16; else bf16 agg
    const unsigned short* __restrict__ W1h, const unsigned short* __restrict__ W1l,
    const float* __restrict__ b1,
    const unsigned short* __restrict__ W2h, const unsigned short* __restrict__ W2l,
    const float* __restrict__ b2,
    const unsigned short* __restrict__ P1h, const float* __restrict__ pb1,
    const unsigned short* __restrict__ P2h, const float* __restrict__ pb2,
    const float* __restrict__ P3, const float* __restrict__ pb3,
    float* __restrict__ out, int M)
{
    __shared__ unsigned short U[MROWS * 256];   // 32 KB: h_in -> h1 -> h -> p1
    __shared__ float red[8 * MROWS];            // 2 KB

    const int wave = threadIdx.x >> 6;          // 0..7
    const int lane = threadIdx.x & 63;
    const int lr   = lane & 15;
    const int quad = lane >> 4;
    const int lk   = quad * 8;
    const int rbase = quad * 4;
    const int row0 = blockIdx.x * MROWS;
    const int ntg0 = wave * 2;                  // 2 col-tiles (32 cols) per wave

    // ---- U[idx128] = h_in: 64 rows x 128 cols ----
    {
        int r = threadIdx.x >> 3;            // 0..63
        int q = threadIdx.x & 7;             // 0..7, 16 cols each
        int gr = row0 + r; if (gr >= M) gr = M - 1;
        #pragma unroll
        for (int c8 = 0; c8 < 2; ++c8) {
            int c0 = q * 16 + c8 * 8;
            if (HIN) {
                uint4 v = *(const uint4*)(hin + (size_t)gr * 128 + c0);
                *(uint4*)&U[idx128(r, c0)] = v;
            } else {
                const unsigned short* ar = hin + (size_t)gr * 128 + c0;
                uint4 u = *(const uint4*)ar;
                float av[8];
                av[0]=b2f((unsigned short)(u.x&0xffff)); av[1]=b2f((unsigned short)(u.x>>16));
                av[2]=b2f((unsigned short)(u.y&0xffff)); av[3]=b2f((unsigned short)(u.y>>16));
                av[4]=b2f((unsigned short)(u.z&0xffff)); av[5]=b2f((unsigned short)(u.z>>16));
                av[6]=b2f((unsigned short)(u.w&0xffff)); av[7]=b2f((unsigned short)(u.w>>16));
                const float* xr = x + (size_t)gr * 127;
                union { unsigned short u[8]; uint4 v; } ob;
                #pragma unroll
                for (int j = 0; j < 8; ++j) {
                    int f = c0 + j;
                    float xval = (f < 127) ? xr[f] : t[gr];
                    ob.u[j] = f2b(xval + av[j]);
                }
                *(uint4*)&U[idx128(r, c0)] = ob.v;
            }
        }
    }
    __syncthreads();

    f32x4 acc[4][2];
    const f32x4 zero = {0.f, 0.f, 0.f, 0.f};

    // ======== stage 1: h1 = relu(h_in @ W1 + b1); U := h1 ========
    #pragma unroll
    for (int nt = 0; nt < 2; ++nt)
        #pragma unroll
        for (int rt = 0; rt < 4; ++rt) acc[rt][nt] = zero;

    for (int kt = 0; kt < 4; ++kt) {
        bf16x8 a[4];
        #pragma unroll
        for (int rt = 0; rt < 4; ++rt)
            a[rt] = *(const bf16x8*)&U[idx128(rt * 16 + lr, kt * 32 + lk)];
        #pragma unroll
        for (int nt = 0; nt < 2; ++nt) {
            size_t bofs = (size_t)((kt * 16 + ntg0 + nt) * 64 + lane) * 8;
            bf16x8 bh = *(const bf16x8*)(W1h + bofs);
            bf16x8 bl = *(const bf16x8*)(W1l + bofs);
            #pragma unroll
            for (int rt = 0; rt < 4; ++rt) {
                acc[rt][nt] = __builtin_amdgcn_mfma_f32_16x16x32_bf16(a[rt], bl, acc[rt][nt], 0, 0, 0);
                acc[rt][nt] = __builtin_amdgcn_mfma_f32_16x16x32_bf16(a[rt], bh, acc[rt][nt], 0, 0, 0);
            }
        }
    }
    __syncthreads();
    #pragma unroll
    for (int nt = 0; nt < 2; ++nt) {
        int col = (ntg0 + nt) * 16 + lr;
        float bv = b1[col];
        #pragma unroll
        for (int rt = 0; rt < 4; ++rt)
            #pragma unroll
            for (int r4 = 0; r4 < 4; ++r4)
                U[idx256(rt * 16 + rbase + r4, col)] = f2b(fmaxf(acc[rt][nt][r4] + bv, 0.f));
    }
    __syncthreads();

    // ======== stage 2: h = tanh(relu(h1 @ W2 + b2)); U := h ========
    #pragma unroll
    for (int nt = 0; nt < 2; ++nt)
        #pragma unroll
        for (int rt = 0; rt < 4; ++rt) acc[rt][nt] = zero;

    for (int kt = 0; kt < 8; ++kt) {
        bf16x8 a[4];
        #pragma unroll
        for (int rt = 0; rt < 4; ++rt)
            a[rt] = *(const bf16x8*)&U[idx256(rt * 16 + lr, kt * 32 + lk)];
        #pragma unroll
        for (int nt = 0; nt < 2; ++nt) {
            size_t bofs = (size_t)((kt * 16 + ntg0 + nt) * 64 + lane) * 8;
            bf16x8 bh = *(const bf16x8*)(W2h + bofs);
            bf16x8 bl = *(const bf16x8*)(W2l + bofs);
            #pragma unroll
            for (int rt = 0; rt < 4; ++rt) {
                acc[rt][nt] = __builtin_amdgcn_mfma_f32_16x16x32_bf16(a[rt], bl, acc[rt][nt], 0, 0, 0);
                acc[rt][nt] = __builtin_amdgcn_mfma_f32_16x16x32_bf16(a[rt], bh, acc[rt][nt], 0, 0, 0);
            }
        }
    }
    __syncthreads();
    #pragma unroll
    for (int nt = 0; nt < 2; ++nt) {
        int col = (ntg0 + nt) * 16 + lr;
        float bv = b2[col];
        #pragma unroll
        for (int rt = 0; rt < 4; ++rt)
            #pragma unroll
            for (int r4 = 0; r4 < 4; ++r4) {
                float v = fmaxf(acc[rt][nt][r4] + bv, 0.f);   // relu∘tanh == tanh∘relu
                float e = __expf(-2.f * v);
                U[idx256(rt * 16 + rbase + r4, col)] = f2b((1.f - e) / (1.f + e));
            }
    }
    __syncthreads();

    // ======== stage 3: p1 = lrelu([h | x_in] @ P1 + pb1); U := p1 ========
    #pragma unroll
    for (int nt = 0; nt < 2; ++nt)
        #pragma unroll
        for (int rt = 0; rt < 4; ++rt) acc[rt][nt] = zero;

    for (int kt = 0; kt < 12; ++kt) {
        bf16x8 a[4];
        if (kt < 8) {
            #pragma unroll
            for (int rt = 0; rt < 4; ++rt)
                a[rt] = *(const bf16x8*)&U[idx256(rt * 16 + lr, kt * 32 + lk)];
        } else if (HIN) {
            #pragma unroll
            for (int rt = 0; rt < 4; ++rt) {
                int r = row0 + rt * 16 + lr; if (r >= M) r = M - 1;
                int c0 = (kt - 8) * 32 + lk;
                a[rt] = *(const bf16x8*)(xb + (size_t)r * 128 + c0);
            }
        } else {
            #pragma unroll
            for (int rt = 0; rt < 4; ++rt) {
                int r = row0 + rt * 16 + lr; if (r >= M) r = M - 1;
                int c0 = (kt - 8) * 32 + lk;
                const float* xr = x + (size_t)r * 127;
                union { unsigned short u[8]; bf16x8 v; } au;
                #pragma unroll
                for (int j = 0; j < 8; ++j) {
                    int f = c0 + j;
                    au.u[j] = f2b((f < 127) ? xr[f] : t[r]);
                }
                a[rt] = au.v;
            }
        }
        #pragma unroll
        for (int nt = 0; nt < 2; ++nt) {
            size_t bofs = (size_t)((kt * 16 + ntg0 + nt) * 64 + lane) * 8;
            bf16x8 bh = *(const bf16x8*)(P1h + bofs);
            #pragma unroll
            for (int rt = 0; rt < 4; ++rt)
                acc[rt][nt] = __builtin_amdgcn_mfma_f32_16x16x32_bf16(a[rt], bh, acc[rt][nt], 0, 0, 0);
        }
    }
    __syncthreads();
    #pragma unroll
    for (int nt = 0; nt < 2; ++nt) {
        int col = (ntg0 + nt) * 16 + lr;
        float bv = pb1[col];
        #pragma unroll
        for (int rt = 0; rt < 4; ++rt)
            #pragma unroll
            for (int r4 = 0; r4 < 4; ++r4) {
                float v = acc[rt][nt][r4] + bv;
                U[idx256(rt * 16 + rbase + r4, col)] = f2b((v > 0.f) ? v : 0.2f * v);
            }
    }
    __syncthreads();

    // ======== stage 4: p2 = lrelu(p1 @ P2 + pb2); pred = p2 . P3 + pb3 ========
    #pragma unroll
    for (int nt = 0; nt < 2; ++nt)
        #pragma unroll
        for (int rt = 0; rt < 4; ++rt) acc[rt][nt] = zero;

    for (int kt = 0; kt < 8; ++kt) {
        bf16x8 a[4];
        #pragma unroll
        for (int rt = 0; rt < 4; ++rt)
            a[rt] = *(const bf16x8*)&U[idx256(rt * 16 + lr, kt * 32 + lk)];
        #pragma unroll
        for (int nt = 0; nt < 2; ++nt) {
            size_t bofs = (size_t)((kt * 16 + ntg0 + nt) * 64 + lane) * 8;
            bf16x8 bh = *(const bf16x8*)(P2h + bofs);
            #pragma unroll
            for (int rt = 0; rt < 4; ++rt)
                acc[rt][nt] = __builtin_amdgcn_mfma_f32_16x16x32_bf16(a[rt], bh, acc[rt][nt], 0, 0, 0);
        }
    }
    float part[4][4];
    #pragma unroll
    for (int rt = 0; rt < 4; ++rt)
        #pragma unroll
        for (int r4 = 0; r4 < 4; ++r4) part[rt][r4] = 0.f;
    #pragma unroll
    for (int nt = 0; nt < 2; ++nt) {
        int col = (ntg0 + nt) * 16 + lr;
        float bv = pb2[col];
        float p3 = P3[col];
        #pragma unroll
        for (int rt = 0; rt < 4; ++rt)
            #pragma unroll
            for (int r4 = 0; r4 < 4; ++r4) {
                float v = acc[rt][nt][r4] + bv;
                v = (v > 0.f) ? v : 0.2f * v;
                part[rt][r4] += v * p3;
            }
    }
    #pragma unroll
    for (int rt = 0; rt < 4; ++rt)
        #pragma unroll
        for (int r4 = 0; r4 < 4; ++r4) {
            float s = part[rt][r4];
            s += __shfl_xor(s, 1);
            s += __shfl_xor(s, 2);
            s += __shfl_xor(s, 4);
            s += __shfl_xor(s, 8);
            if (lr == 0) red[wave * MROWS + rt * 16 + rbase + r4] = s;
        }
    __syncthreads();
    if ((int)threadIdx.x < MROWS) {
        int row = row0 + threadIdx.x;
        if (row < M) {
            float s = pb3[0];
            #pragma unroll
            for (int w = 0; w < 8; ++w) s += red[w * MROWS + threadIdx.x];
            out[M + row] = s;
        }
    }
}

extern "C" void kernel_launch(void* const* d_in, const int* in_sizes, int n_in,
                              void* d_out, int out_size, void* d_ws, size_t ws_size,
                              hipStream_t stream)
{
    const int M = in_sizes[1];                 // 50000
    const int E = in_sizes[3] / 2;             // 800000
    const float* x   = (const float*)d_in[0];
    const float* t   = (const float*)d_in[1];
    const int*   ei  = (const int*)d_in[3];
    const float* W1  = (const float*)d_in[4];
    const float* b1  = (const float*)d_in[5];
    const float* W2  = (const float*)d_in[6];
    const float* b2  = (const float*)d_in[7];
    const float* P1  = (const float*)d_in[8];
    const float* pb1 = (const float*)d_in[9];
    const float* P2  = (const float*)d_in[10];
    const float* pb2 = (const float*)d_in[11];
    const float* P3  = (const float*)d_in[12];
    const float* pb3 = (const float*)d_in[13];
    float* out = (float*)d_out;

    const size_t hinB  = (size_t)M * 128 * 2;   // bf16 h_in (or bf16 agg in fallback)
    const size_t xbB   = (size_t)M * 128 * 2;
    const size_t wB    = (size_t)(128 * 2 + 256 * 2 + 384 + 256) * 256 * 2;  // 720 KB
    const size_t sortB = (size_t)E * 4;
    const int    nb    = (M + 255) / 256;       // 196 scan blocks (<= 256 for co-residency)
    const size_t csrB  = (size_t)(3 * M + 2 + nb) * 4;
    char* ws = (char*)d_ws;
    auto al = [](size_t v) { return (v + 255) & ~(size_t)255; };

    bool tier = (ws_size >= al(hinB) + al(xbB) + al(wB) + al(sortB) + al(csrB) + 4096) && nb <= 256;

    unsigned short* hin = (unsigned short*)ws;
    unsigned short* xb  = (unsigned short*)(ws + al(hinB));
    unsigned short* W1h = (unsigned short*)((char*)xb + al(xbB));
    unsigned short* W1l = W1h + 128 * 256;
    unsigned short* W2h = W1l + 128 * 256;
    unsigned short* W2l = W2h + 256 * 256;
    unsigned short* P1h = W2l + 256 * 256;
    unsigned short* P2h = P1h + 384 * 256;
    int* sorted = (int*)(P2h + 256 * 256);
    int* count  = sorted + E;
    int* start  = count + M;        // M+1 entries
    int* cursor = start + M + 1;
    unsigned* state = (unsigned*)(cursor + M);

    const int NM = (M + MROWS - 1) / MROWS;
    int prepN = (M * 16 > E) ? M * 16 : E;
    int prepB = (prepN + 255) / 256;
    int reoB  = ((E + 3) / 4 + 255) / 256;

    if (tier) {
        hipMemsetAsync(count, 0, (size_t)M * 4, stream);   // only cross-phase order need
        fused_prep_kernel<<<prepB, 256, 0, stream>>>(
            x, t, ei, W1, W2, P1, P2, W1h, W1l, W2h, W2l, P1h, P2h,
            xb, count, out, state, E, M, nb);
        scan_fused_kernel<<<nb, 256, 0, stream>>>(count, start, cursor, state, M, nb);
        reorder_csr_kernel<<<reoB, 256, 0, stream>>>(ei, cursor, sorted, E, M);
        gather_csr_kernel<<<(M + 15) / 16, 256, 0, stream>>>(xb, sorted, start, hin, M);
        mega_kernel<true><<<NM, 512, 0, stream>>>(
            x, t, xb, hin, W1h, W1l, b1, W2h, W2l, b2,
            P1h, pb1, P2h, pb2, P3, pb3, out, M);
    } else {
        pack_all_init_kernel<<<1024, 256, 0, stream>>>(
            W1, W2, P1, P2, W1h, W1l, W2h, W2l, P1h, P2h, M);
        int pxb = (M * 128 + 255) / 256;
        prep_kernel<<<pxb, 256, 0, stream>>>(hin, out, M);
        scatter_kernel<<<(E + 7) / 8, 256, 0, stream>>>(ei, x, t, hin, E, M);
        mega_kernel<false><<<NM, 512, 0, stream>>>(
            x, t, nullptr, hin, W1h, W1l, b1, W2h, W2l, b2,
            P1h, pb1, P2h, pb2, P3, pb3, out, M);
    }
}